// Round 2
// baseline (62.691 us; speedup 1.0000x reference)
//
#include <hip/hip_runtime.h>
#include <hip/hip_bf16.h>

// VQ-VAE vector quantizer, MI355X — fused 3-kernel pipeline.
// [k_prep]  emb fp32 -> E bf16 + cn = ||e_k||^2
// [k_main]  per 64-row block: transpose lat->bf16 A-tile (LDS), row norms (fp32),
//           scores = cn - 2*A.E^T via mfma_16x16x32_bf16 (E reg-prefetched),
//           running argmin, fused q = emb[k*] gather/store, loss = s* + ||lat||^2
// [k_final] vq_loss = 1.25 * sum / (N*D)

#define NPOS 32768
#define DIM  128
#define KCB  1024

typedef __attribute__((ext_vector_type(8))) short bf16x8;
typedef __attribute__((ext_vector_type(4))) float f32x4;

// workspace layout (bytes)
#define WS_E 0u         // bf16 [1024][128] = 262144
#define WS_C 262144u    // f32  [1024]      = 4096
#define WS_P 266240u    // f32  [512]       = 2048

static __device__ inline short f2bf(float f) {
    __hip_bfloat16 h = __float2bfloat16(f);
    return *reinterpret_cast<short*>(&h);
}

// ---------------- codebook prep: bf16 copy + squared norms ----------------
__global__ __launch_bounds__(128) void k_prep(const float* __restrict__ emb,
                                              __hip_bfloat16* __restrict__ E,
                                              float* __restrict__ cn) {
    int k = blockIdx.x, d = threadIdx.x;
    float v = emb[(k << 7) + d];
    E[(k << 7) + d] = __float2bfloat16(v);
    float s = v * v;
#pragma unroll
    for (int m = 1; m < 64; m <<= 1) s += __shfl_xor(s, m);
    __shared__ float sh[2];
    if ((threadIdx.x & 63) == 0) sh[threadIdx.x >> 6] = s;
    __syncthreads();
    if (threadIdx.x == 0) cn[k] = sh[0] + sh[1];
}

// ---------------- fused main ----------------
// grid 512 x 256thr (4 waves). Block owns rows n = bm*64..+64 (one b, hw range 64).
// LDS: A (64x256B swz, 16K) | T fp32 [128d][64hw] 32K (reused as E tile) |
//      cn 4K | rn4 1K | cand_s 1K | cand_i 1K   = 56320 B -> 2 blocks/CU.
__global__ __launch_bounds__(256) void k_main(const float* __restrict__ lat,
                                              const float* __restrict__ emb,
                                              const __hip_bfloat16* __restrict__ E,
                                              const float* __restrict__ cn,
                                              float* __restrict__ outq,
                                              float* __restrict__ partial) {
    __shared__ char lds[56320];
    char*  ldsA = lds;                         // bf16 A tile, swizzled
    char*  ldsE = lds + 16384;                 // E tile (after transpose done)
    float* Tf   = (float*)(lds + 16384);       // fp32 transpose staging
    float* cnl  = (float*)(lds + 49152);
    float* rn4  = (float*)(lds + 53248);       // [4][64] row-norm partials
    float* cs   = (float*)(lds + 54272);       // [4][64] per-wave best score
    int*   ci   = (int*)  (lds + 55296);       // [4][64] per-wave best idx

    const int t = threadIdx.x, bm = blockIdx.x;
    const int lane = t & 63, wid = t >> 6;
    const int l15 = lane & 15, lg = lane >> 4;
    const int b = bm >> 4, hw0 = (bm & 15) << 6;
    const float* latb = lat + ((size_t)b << 17) + hw0;

    // prefetch E tile 0 + cn (consumed after transpose phase)
    uint4 er[8];
    {
        const uint4* Eg = (const uint4*)E;
#pragma unroll
        for (int i = 0; i < 8; ++i) er[i] = Eg[i * 256 + t];
    }
    float4 cnv = ((const float4*)cn)[t];

    // ---- stage A: coalesced float4 reads -> fp32 T[d][hw] ----
    float4 la[8];
#pragma unroll
    for (int i = 0; i < 8; ++i) {
        int idx = i * 256 + t;                  // d = idx>>4 (128), hw4 = (idx&15)*4
        la[i] = *(const float4*)(latb + (size_t)(idx >> 4) * 1024 + ((idx & 15) << 2));
    }
#pragma unroll
    for (int i = 0; i < 8; ++i) {
        int idx = i * 256 + t;
        *(float4*)(Tf + (idx >> 4) * 64 + ((idx & 15) << 2)) = la[i];
    }
    ((float4*)cnl)[t] = cnv;
    __syncthreads();

    // ---- transpose-read: T columns -> bf16x8 -> swizzled A tile; fp32 row norms ----
    {
        int row = t & 63;
        float rn = 0.f;
#pragma unroll
        for (int i = 0; i < 4; ++i) {
            int c16 = i * 4 + (t >> 6);
            bf16x8 s;
#pragma unroll
            for (int j = 0; j < 8; ++j) {
                float f = Tf[(c16 * 8 + j) * 64 + row];
                rn = fmaf(f, f, rn);
                s[j] = f2bf(f);
            }
            *(bf16x8*)(ldsA + row * 256 + ((c16 * 16) ^ ((row & 7) << 4))) = s;
        }
        rn4[(t >> 6) * 64 + row] = rn;
    }

    float run_s[4][4]; int run_i[4][4];
#pragma unroll
    for (int m = 0; m < 4; ++m)
#pragma unroll
        for (int r = 0; r < 4; ++r) { run_s[m][r] = 3.0e38f; run_i[m][r] = 0; }

    // ---- main loop: 8 E-tiles of 128 codes ----
    for (int ct = 0; ct < 8; ++ct) {
        __syncthreads();   // T reads done (ct==0) / prev MFMA frag reads done
#pragma unroll
        for (int i = 0; i < 8; ++i) {
            int chunk = i * 256 + t, row = chunk >> 4, c16 = chunk & 15;
            *(uint4*)(ldsE + row * 256 + ((c16 * 16) ^ ((row & 7) << 4))) = er[i];
        }
        __syncthreads();
        if (ct < 7) {      // prefetch next tile into regs; hides under MFMA
            const uint4* Eg = (const uint4*)(E + ((size_t)(ct + 1) << 14));
#pragma unroll
            for (int i = 0; i < 8; ++i) er[i] = Eg[i * 256 + t];
        }

        f32x4 acc[4][2];
#pragma unroll
        for (int m = 0; m < 4; ++m)
#pragma unroll
            for (int c = 0; c < 2; ++c) acc[m][c] = (f32x4){0.f, 0.f, 0.f, 0.f};

#pragma unroll
        for (int ks = 0; ks < 4; ++ks) {
            int cb = ks * 64 + lg * 16;
            bf16x8 af[4], bfv[2];
#pragma unroll
            for (int m = 0; m < 4; ++m) {
                int r = m * 16 + l15;
                af[m] = *(const bf16x8*)(ldsA + r * 256 + (cb ^ ((r & 7) << 4)));
            }
#pragma unroll
            for (int c = 0; c < 2; ++c) {
                int rr = wid * 32 + c * 16 + l15;
                bfv[c] = *(const bf16x8*)(ldsE + rr * 256 + (cb ^ ((rr & 7) << 4)));
            }
#pragma unroll
            for (int m = 0; m < 4; ++m)
#pragma unroll
                for (int c = 0; c < 2; ++c)
                    acc[m][c] = __builtin_amdgcn_mfma_f32_16x16x32_bf16(af[m], bfv[c], acc[m][c], 0, 0, 0);
        }

        // fold into running argmin (k ascending; strict < keeps lowest idx)
#pragma unroll
        for (int c = 0; c < 2; ++c) {
            int kg = ct * 128 + wid * 32 + c * 16 + l15;
            float cv = cnl[kg];
#pragma unroll
            for (int m = 0; m < 4; ++m)
#pragma unroll
                for (int r = 0; r < 4; ++r) {
                    float s = fmaf(-2.0f, acc[m][c][r], cv);
                    if (s < run_s[m][r]) { run_s[m][r] = s; run_i[m][r] = kg; }
                }
        }
    }

    // ---- butterfly over the 16 lanes sharing each C-row, then per-wave cand ----
#pragma unroll
    for (int m = 0; m < 4; ++m)
#pragma unroll
        for (int r = 0; r < 4; ++r) {
            float s = run_s[m][r]; int bi = run_i[m][r];
#pragma unroll
            for (int mask = 1; mask < 16; mask <<= 1) {
                float os = __shfl_xor(s, mask);
                int   oi = __shfl_xor(bi, mask);
                if (os < s || (os == s && oi < bi)) { s = os; bi = oi; }
            }
            if (l15 == 0) {
                int row = m * 16 + lg * 4 + r;
                cs[wid * 64 + row] = s;
                ci[wid * 64 + row] = bi;
            }
        }
    __syncthreads();

    // ---- combine 4 waves, gather q = emb[k*] (fp32), store [B,D,H,W], loss ----
    {
        int hwl = t & 63, dh = t >> 6;
        float bs = cs[hwl]; int bi = ci[hwl];
#pragma unroll
        for (int w = 1; w < 4; ++w) {
            float s2 = cs[w * 64 + hwl]; int i2 = ci[w * 64 + hwl];
            if (s2 < bs || (s2 == bs && i2 < bi)) { bs = s2; bi = i2; }
        }
        const float4* eg = (const float4*)(emb + ((size_t)bi << 7) + dh * 32);
        float* ob = outq + ((size_t)b << 17) + (size_t)(dh * 32) * 1024 + hw0 + hwl;
#pragma unroll
        for (int j = 0; j < 8; ++j) {
            float4 v = eg[j];
            ob[(size_t)(j * 4 + 0) * 1024] = v.x;
            ob[(size_t)(j * 4 + 1) * 1024] = v.y;
            ob[(size_t)(j * 4 + 2) * 1024] = v.z;
            ob[(size_t)(j * 4 + 3) * 1024] = v.w;
        }
        if (t < 64) {   // wave 0: loss partial = sum_rows (s* + ||lat_row||^2)
            float p = bs + rn4[hwl] + rn4[64 + hwl] + rn4[128 + hwl] + rn4[192 + hwl];
#pragma unroll
            for (int m = 1; m < 64; m <<= 1) p += __shfl_xor(p, m);
            if (t == 0) partial[bm] = p;
        }
    }
}

__global__ __launch_bounds__(256) void k_final(const float* __restrict__ partial,
                                               float* __restrict__ loss) {
    float s = partial[threadIdx.x] + partial[threadIdx.x + 256];
#pragma unroll
    for (int m = 1; m < 64; m <<= 1) s += __shfl_xor(s, m);
    __shared__ float sh[4];
    if ((threadIdx.x & 63) == 0) sh[threadIdx.x >> 6] = s;
    __syncthreads();
    if (threadIdx.x == 0) loss[0] = (sh[0] + sh[1] + sh[2] + sh[3]) * (1.25f / 4194304.0f);
}

extern "C" void kernel_launch(void* const* d_in, const int* in_sizes, int n_in,
                              void* d_out, int out_size, void* d_ws, size_t ws_size,
                              hipStream_t stream) {
    const float* lat = (const float*)d_in[0];   // [32,128,32,32]
    const float* emb = (const float*)d_in[1];   // [1024,128]
    float* out = (float*)d_out;                 // q (4194304) + vq_loss (1)
    char* ws = (char*)d_ws;
    __hip_bfloat16* E = (__hip_bfloat16*)(ws + WS_E);
    float* cn  = (float*)(ws + WS_C);
    float* prt = (float*)(ws + WS_P);

    k_prep <<<1024, 128, 0, stream>>>(emb, E, cn);
    k_main <<<512,  256, 0, stream>>>(lat, emb, E, cn, out, prt);
    k_final<<<1,    256, 0, stream>>>(prt, out + 4194304);
}